// Round 3
// baseline (468.591 us; speedup 1.0000x reference)
//
#include <hip/hip_runtime.h>
#include <stdint.h>

// ---------------- problem constants ----------------
constexpr int B  = 4, S = 8256, H = 768, NH = 12, HD = 64;
constexpr int M  = B * S;        // 33024 rows
constexpr int N3 = 3 * H;        // 2304 fused QKV cols
// workspace layout (bytes)
constexpr long XB_OFF   = 0;
constexpr long XB_BYTES = (long)M * H * 2;        // 50,724,864  f16 X
constexpr long W_OFF    = XB_OFF + XB_BYTES;
constexpr long W_BYTES  = (long)N3 * H * 2;       // 3,538,944   f16 Wq|Wk|Wv
constexpr long ROPE_OFF = W_OFF + W_BYTES;
constexpr long ROPE_BYTES = 128 * 32 * 2 * 4;     // 32 KB cos/sin table
constexpr long QKV_OFF  = ROPE_OFF + ROPE_BYTES;
constexpr long QKV_BYTES = (long)M * N3 * 2;      // 152,174,592 f16 QKV (rope applied)
constexpr long WS_NEEDED = QKV_OFF + QKV_BYTES;   // ~197 MB

typedef __attribute__((ext_vector_type(8))) _Float16 h8;        // 8 f16 = 4 VGPR (MFMA operand)
typedef __attribute__((ext_vector_type(8))) unsigned short us8;
typedef __attribute__((ext_vector_type(4))) float f4;

#define MFMA16(a,b,c) __builtin_amdgcn_mfma_f32_16x16x32_f16((a),(b),(c),0,0,0)
#define GLL16(gp, lp) __builtin_amdgcn_global_load_lds( \
    (__attribute__((address_space(1))) void*)(gp),      \
    (__attribute__((address_space(3))) void*)(lp), 16, 0, 0)

static __device__ __forceinline__ unsigned short f2h(float x) {  // RNE f32->f16
  _Float16 h = (_Float16)x;
  return __builtin_bit_cast(unsigned short, h);
}
static __device__ __forceinline__ f4 f4z() { f4 z = {0.f,0.f,0.f,0.f}; return z; }

// ================= prep: fp32->f16 converts + rope table =================
// blocks [0,12384): X   | [12384,13248): Wq/Wk/Wv | [13248,13264): rope table
__global__ __launch_bounds__(256) void prep_kernel(
    const float* __restrict__ X,
    const float* __restrict__ Wq, const float* __restrict__ Wk, const float* __restrict__ Wv,
    unsigned short* __restrict__ Xb, unsigned short* __restrict__ Wcat, float* __restrict__ rope)
{
  int bid = blockIdx.x;
  if (bid < 12384) {
    long base = (long)bid * 2048 + threadIdx.x * 8;
    float4 v0 = *(const float4*)(X + base);
    float4 v1 = *(const float4*)(X + base + 4);
    us8 o;
    o[0]=f2h(v0.x); o[1]=f2h(v0.y); o[2]=f2h(v0.z); o[3]=f2h(v0.w);
    o[4]=f2h(v1.x); o[5]=f2h(v1.y); o[6]=f2h(v1.z); o[7]=f2h(v1.w);
    *(us8*)(Xb + base) = o;
  } else if (bid < 13248) {
    int wb  = bid - 12384;
    int mat = wb / 288;
    int base = (wb % 288) * 2048 + threadIdx.x * 8;
    const float* src = (mat == 0) ? Wq : (mat == 1) ? Wk : Wv;
    float4 v0 = *(const float4*)(src + base);
    float4 v1 = *(const float4*)(src + base + 4);
    us8 o;
    o[0]=f2h(v0.x); o[1]=f2h(v0.y); o[2]=f2h(v0.z); o[3]=f2h(v0.w);
    o[4]=f2h(v1.x); o[5]=f2h(v1.y); o[6]=f2h(v1.z); o[7]=f2h(v1.w);
    *(us8*)(Wcat + (long)mat * 589824 + base) = o;
  } else {
    int t = (bid - 13248) * 256 + threadIdx.x;   // 4096 = 128 pos x 32 freq
    int p = t >> 5, i = t & 31;
    double ang = (double)p * pow(10000.0, -(double)i / 32.0);
    rope[2*t]   = (float)cos(ang);
    rope[2*t+1] = (float)sin(ang);
  }
}

// ================= fused QKV GEMM (+bias +RoPE epilogue) =================
// Y[M][2304] = X[M][768] @ Wcat[2304][768]^T ; 128x128 tile, BK=64, 4 waves.
__global__ __launch_bounds__(256) void qkv_gemm(
    const unsigned short* __restrict__ Xb, const unsigned short* __restrict__ Wb,
    const float* __restrict__ bqp, const float* __restrict__ bkp, const float* __restrict__ bvp,
    const float* __restrict__ rope, unsigned short* __restrict__ QKV)
{
  __shared__ __align__(16) unsigned char ldsA[128 * 128];  // 128 rows x 64 f16 (128B), swizzled
  __shared__ __align__(16) unsigned char ldsB[128 * 128];
  const int tid = threadIdx.x, lane = tid & 63, wid = tid >> 6;
  const int bid = blockIdx.x;
  const int mt = bid % (M / 128);
  const int nt = bid / (M / 128);
  const long m0 = (long)mt * 128;
  const int  n0 = nt * 128;
  const int wm = wid >> 1, wn = wid & 1;

  f4 acc[4][4];
  #pragma unroll
  for (int i = 0; i < 4; ++i)
    #pragma unroll
    for (int j = 0; j < 4; ++j) acc[i][j] = f4z();

  const char* Xc = (const char*)Xb;
  const char* Wc = (const char*)Wb;

  for (int kt = 0; kt < 768 / 64; ++kt) {
    const int k0b = kt * 128;                      // byte offset of K-slice
    #pragma unroll
    for (int i = 0; i < 4; ++i) {
      const int ob = ((i << 2) + wid) * 1024;      // wave-uniform LDS base
      const int o  = ob + lane * 16;               // linear dest byte this lane fills
      const int row = o >> 7, cb = o & 127;
      const int csrc = cb ^ ((row & 7) << 4);      // pre-swizzled source (rule 21)
      GLL16(Xc + (m0 + row) * 1536 + k0b + csrc, ldsA + ob);
      GLL16(Wc + (long)(n0 + row) * 1536 + k0b + csrc, ldsB + ob);
    }
    asm volatile("s_waitcnt vmcnt(0)" ::: "memory");
    __syncthreads();
    #pragma unroll
    for (int ks = 0; ks < 2; ++ks) {
      h8 a[4], b[4];
      const int kb = ks * 64 + ((lane >> 4) << 4);
      #pragma unroll
      for (int f = 0; f < 4; ++f) {
        const int ra = wm * 64 + f * 16 + (lane & 15);
        a[f] = *(const h8*)(ldsA + ra * 128 + (kb ^ ((ra & 7) << 4)));
        const int rb = wn * 64 + f * 16 + (lane & 15);
        b[f] = *(const h8*)(ldsB + rb * 128 + (kb ^ ((rb & 7) << 4)));
      }
      #pragma unroll
      for (int fm = 0; fm < 4; ++fm)
        #pragma unroll
        for (int fn = 0; fn < 4; ++fn)
          acc[fm][fn] = MFMA16(a[fm], b[fn], acc[fm][fn]);
    }
    __syncthreads();
  }

  // epilogue: bias + RoPE (wave spans exactly one head: 64 cols) + f16 store
  const int colb = n0 + wn * 64;
  const int sel = (colb >= 1536) ? 2 : (colb >= 768) ? 1 : 0;
  const float* bias = (sel == 0) ? bqp : (sel == 1) ? bkp : bvp;
  const int hcol = colb % 768;
  float bia[4];
  #pragma unroll
  for (int f = 0; f < 4; ++f) bia[f] = bias[hcol + f * 16 + (lane & 15)];

  #pragma unroll
  for (int fm = 0; fm < 4; ++fm) {
    #pragma unroll
    for (int reg = 0; reg < 4; ++reg) {
      const long m = m0 + wm * 64 + fm * 16 + ((lane >> 4) << 2) + reg;
      const int s = (int)(m % (long)S);
      const int pos = (s < 64) ? s : ((s - 64) & 127);
      unsigned short* orow = QKV + m * N3 + colb;
      if (sel < 2) {  // Q or K: rotate (d, d+32) pairs = (fn, fn+2) same lane
        #pragma unroll
        for (int f = 0; f < 2; ++f) {
          const int d1 = f * 16 + (lane & 15);
          const float c  = rope[(pos * 32 + d1) * 2];
          const float sn = rope[(pos * 32 + d1) * 2 + 1];
          const float x1 = acc[fm][f][reg]     + bia[f];
          const float x2 = acc[fm][f + 2][reg] + bia[f + 2];
          orow[f * 16 + (lane & 15)]       = f2h(x1 * c - x2 * sn);
          orow[(f + 2) * 16 + (lane & 15)] = f2h(x2 * c + x1 * sn);
        }
      } else {        // V: bias only
        #pragma unroll
        for (int f = 0; f < 4; ++f)
          orow[f * 16 + (lane & 15)] = f2h(acc[fm][f][reg] + bia[f]);
      }
    }
  }
}

// ================= attention (one block per (b, window, head)) =================
// T=128 local windows, T=64 global head block. 4 waves; wave owns 32 Q rows.
template <int T>
__global__ __launch_bounds__(256) void attn_kernel(
    const unsigned short* __restrict__ QKV, float* __restrict__ out)
{
  constexpr int NF  = T / 16;   // col fragments of scores
  constexpr int NKS = T / 32;   // k-steps of PV
  __shared__ __align__(16) unsigned char sVT[16384];   // V^T [64 d][128 j] f16, chunk^=(d&15)
  __shared__ __align__(16) unsigned char sP[4][8192];  // per-wave P [32][128] f16, swizzled

  const int tid = threadIdx.x, lane = tid & 63, w = tid >> 6;
  int bid = blockIdx.x;
  const int h = bid % NH; bid /= NH;
  long row0;
  if (T == 64) row0 = (long)bid * S;
  else { const int ww = bid % 64; const int b = bid / 64; row0 = (long)b * S + 64 + (long)ww * 128; }
  const unsigned short* Qb = QKV + row0 * N3 + h * HD;
  const unsigned short* Kb = Qb + H;
  const unsigned short* Vb = Qb + 2 * H;

  // ---- stage V^T: wave = 16-d chunk, lane = token pair (conflict-free b32 writes) ----
  {
    const int p = lane;
    if (2 * p + 1 < T) {
      const unsigned short* v0 = Vb + (long)(2 * p) * N3 + w * 16;
      const unsigned short* v1 = v0 + N3;
      us8 a0 = *(const us8*)(v0);
      us8 a1 = *(const us8*)(v0 + 8);
      us8 c0 = *(const us8*)(v1);
      us8 c1 = *(const us8*)(v1 + 8);
      #pragma unroll
      for (int i = 0; i < 8; ++i) {
        const int d = w * 16 + i, d2 = d + 8;
        *(unsigned*)(sVT + d  * 256 + ((4 * p) ^ ((d  & 15) << 4))) = (unsigned)a0[i] | ((unsigned)c0[i] << 16);
        *(unsigned*)(sVT + d2 * 256 + ((4 * p) ^ ((d2 & 15) << 4))) = (unsigned)a1[i] | ((unsigned)c1[i] << 16);
      }
    }
  }
  __syncthreads();

  if (w * 32 < T) {
    // Q fragments straight from global (A-layout: m=lane&15, k=(lane>>4)*8)
    h8 aq[2][2];
    #pragma unroll
    for (int fm = 0; fm < 2; ++fm)
      #pragma unroll
      for (int ks = 0; ks < 2; ++ks) {
        const long r = w * 32 + fm * 16 + (lane & 15);
        aq[fm][ks] = *(const h8*)(Qb + r * N3 + ks * 32 + ((lane >> 4) << 3));
      }

    // ---- S = Q K^T (K B-frags from global) ----
    f4 acc[2][NF];
    #pragma unroll
    for (int i = 0; i < 2; ++i)
      #pragma unroll
      for (int f = 0; f < NF; ++f) acc[i][f] = f4z();

    #pragma unroll
    for (int f = 0; f < NF; ++f) {
      const long rk = f * 16 + (lane & 15);
      const unsigned short* kr = Kb + rk * N3 + ((lane >> 4) << 3);
      h8 b0 = *(const h8*)(kr);
      h8 b1 = *(const h8*)(kr + 32);
      acc[0][f] = MFMA16(aq[0][0], b0, acc[0][f]);
      acc[0][f] = MFMA16(aq[0][1], b1, acc[0][f]);
      acc[1][f] = MFMA16(aq[1][0], b0, acc[1][f]);
      acc[1][f] = MFMA16(aq[1][1], b1, acc[1][f]);
    }

    // ---- softmax over keys; write normalized P (f16) to per-wave LDS ----
    unsigned char* Pw = sP[w];
    #pragma unroll
    for (int fm = 0; fm < 2; ++fm) {
      #pragma unroll
      for (int reg = 0; reg < 4; ++reg) {
        float mx = -3.0e38f;
        #pragma unroll
        for (int f = 0; f < NF; ++f) mx = fmaxf(mx, acc[fm][f][reg]);
        mx = fmaxf(mx, __shfl_xor(mx, 1));
        mx = fmaxf(mx, __shfl_xor(mx, 2));
        mx = fmaxf(mx, __shfl_xor(mx, 4));
        mx = fmaxf(mx, __shfl_xor(mx, 8));
        float pv[NF], sum = 0.f;
        #pragma unroll
        for (int f = 0; f < NF; ++f) {
          const float p = __expf((acc[fm][f][reg] - mx) * 0.125f);  // /sqrt(64) folded in
          pv[f] = p; sum += p;
        }
        sum += __shfl_xor(sum, 1);
        sum += __shfl_xor(sum, 2);
        sum += __shfl_xor(sum, 4);
        sum += __shfl_xor(sum, 8);
        const float inv = 1.0f / sum;
        const int rloc = fm * 16 + ((lane >> 4) << 2) + reg;
        const int swz = (rloc & 7) << 4;
        #pragma unroll
        for (int f = 0; f < NF; ++f) {
          const int cb = (f * 16 + (lane & 15)) * 2;
          *(unsigned short*)(Pw + rloc * 256 + (cb ^ swz)) = f2h(pv[f] * inv);
        }
      }
    }

    // ---- ctx = P V ----
    f4 acc2[2][4];
    #pragma unroll
    for (int i = 0; i < 2; ++i)
      #pragma unroll
      for (int j = 0; j < 4; ++j) acc2[i][j] = f4z();

    #pragma unroll
    for (int ks = 0; ks < NKS; ++ks) {
      h8 pa[2], vb[4];
      const int kb = ks * 64 + ((lane >> 4) << 4);
      #pragma unroll
      for (int fm = 0; fm < 2; ++fm) {
        const int rp = fm * 16 + (lane & 15);
        pa[fm] = *(const h8*)(Pw + rp * 256 + (kb ^ ((rp & 7) << 4)));
      }
      #pragma unroll
      for (int df = 0; df < 4; ++df) {
        const int d = df * 16 + (lane & 15);
        vb[df] = *(const h8*)(sVT + d * 256 + (kb ^ ((d & 15) << 4)));
      }
      #pragma unroll
      for (int fm = 0; fm < 2; ++fm)
        #pragma unroll
        for (int df = 0; df < 4; ++df)
          acc2[fm][df] = MFMA16(pa[fm], vb[df], acc2[fm][df]);
    }

    // ---- write ctx fp32 to [B][S][H] ----
    float* ob = out + (row0 + w * 32) * H + h * HD;
    #pragma unroll
    for (int fm = 0; fm < 2; ++fm)
      #pragma unroll
      for (int df = 0; df < 4; ++df)
        #pragma unroll
        for (int reg = 0; reg < 4; ++reg) {
          const long r = fm * 16 + ((lane >> 4) << 2) + reg;
          const int c = df * 16 + (lane & 15);
          ob[r * H + c] = acc2[fm][df][reg];
        }
  }
}

// ================= launcher =================
extern "C" void kernel_launch(void* const* d_in, const int* in_sizes, int n_in,
                              void* d_out, int out_size, void* d_ws, size_t ws_size,
                              hipStream_t stream) {
  const float* X  = (const float*)d_in[0];
  // d_in[1] = attention_mask (unused by the reference math)
  const float* Wq = (const float*)d_in[2];
  const float* bq = (const float*)d_in[3];
  const float* Wk = (const float*)d_in[4];
  const float* bk = (const float*)d_in[5];
  const float* Wv = (const float*)d_in[6];
  const float* bv = (const float*)d_in[7];
  float* out = (float*)d_out;

  if ((long)ws_size < WS_NEEDED) return;  // clean fail if scratch too small

  char* ws = (char*)d_ws;
  unsigned short* Xb   = (unsigned short*)(ws + XB_OFF);
  unsigned short* Wcat = (unsigned short*)(ws + W_OFF);
  float*          rope = (float*)(ws + ROPE_OFF);
  unsigned short* QKV  = (unsigned short*)(ws + QKV_OFF);

  prep_kernel<<<13264, 256, 0, stream>>>(X, Wq, Wk, Wv, Xb, Wcat, rope);
  qkv_gemm<<<(M / 128) * (N3 / 128), 256, 0, stream>>>(Xb, Wcat, bq, bk, bv, rope, QKV);
  attn_kernel<64><<<B * NH, 256, 0, stream>>>(QKV, out);
  attn_kernel<128><<<B * 64 * NH, 256, 0, stream>>>(QKV, out);
}

// Round 6
// 417.958 us; speedup vs baseline: 1.1211x; 1.1211x over previous
//
#include <hip/hip_runtime.h>
#include <stdint.h>

// ---------------- problem constants ----------------
constexpr int B  = 4, S = 8256, H = 768, NH = 12, HD = 64;
constexpr int M  = B * S;        // 33024 rows
constexpr int N3 = 3 * H;        // 2304 fused QKV cols
constexpr int NWG_GEMM = (M / 128) * (N3 / 128);   // 4644
constexpr int XQ8 = NWG_GEMM / 8, XR8 = NWG_GEMM % 8;
// workspace layout (bytes)
constexpr long XB_OFF   = 0;
constexpr long XB_BYTES = (long)M * H * 2;        // 50,724,864  f16 X
constexpr long W_OFF    = XB_OFF + XB_BYTES;
constexpr long W_BYTES  = (long)N3 * H * 2;       // 3,538,944   f16 Wq|Wk|Wv
constexpr long ROPE_OFF = W_OFF + W_BYTES;
constexpr long ROPE_BYTES = 128 * 32 * 2 * 4;     // 32 KB cos/sin table
constexpr long QKV_OFF  = ROPE_OFF + ROPE_BYTES;
constexpr long QKV_BYTES = (long)M * N3 * 2;      // 152,174,592 f16 QKV (rope applied)
constexpr long WS_NEEDED = QKV_OFF + QKV_BYTES;   // ~197 MB

typedef __attribute__((ext_vector_type(8))) _Float16 h8;        // 8 f16 = 4 VGPR (MFMA operand)
typedef __attribute__((ext_vector_type(8))) unsigned short us8;
typedef __attribute__((ext_vector_type(4))) float f4;

#define MFMA16(a,b,c) __builtin_amdgcn_mfma_f32_16x16x32_f16((a),(b),(c),0,0,0)
#define GLL16(gp, lp) __builtin_amdgcn_global_load_lds( \
    (__attribute__((address_space(1))) void*)(gp),      \
    (__attribute__((address_space(3))) void*)(lp), 16, 0, 0)

static __device__ __forceinline__ unsigned short f2h(float x) {  // RNE f32->f16
  _Float16 h = (_Float16)x;
  return __builtin_bit_cast(unsigned short, h);
}
static __device__ __forceinline__ f4 f4z() { f4 z = {0.f,0.f,0.f,0.f}; return z; }

// ================= prep: fp32->f16 converts + rope table =================
// blocks [0,12384): X   | [12384,13248): Wq/Wk/Wv | [13248,13264): rope table
__global__ __launch_bounds__(256) void prep_kernel(
    const float* __restrict__ X,
    const float* __restrict__ Wq, const float* __restrict__ Wk, const float* __restrict__ Wv,
    unsigned short* __restrict__ Xb, unsigned short* __restrict__ Wcat, float* __restrict__ rope)
{
  int bid = blockIdx.x;
  if (bid < 12384) {
    long base = (long)bid * 2048 + threadIdx.x * 8;
    float4 v0 = *(const float4*)(X + base);
    float4 v1 = *(const float4*)(X + base + 4);
    us8 o;
    o[0]=f2h(v0.x); o[1]=f2h(v0.y); o[2]=f2h(v0.z); o[3]=f2h(v0.w);
    o[4]=f2h(v1.x); o[5]=f2h(v1.y); o[6]=f2h(v1.z); o[7]=f2h(v1.w);
    *(us8*)(Xb + base) = o;
  } else if (bid < 13248) {
    int wb  = bid - 12384;
    int mat = wb / 288;
    int base = (wb % 288) * 2048 + threadIdx.x * 8;
    const float* src = (mat == 0) ? Wq : (mat == 1) ? Wk : Wv;
    float4 v0 = *(const float4*)(src + base);
    float4 v1 = *(const float4*)(src + base + 4);
    us8 o;
    o[0]=f2h(v0.x); o[1]=f2h(v0.y); o[2]=f2h(v0.z); o[3]=f2h(v0.w);
    o[4]=f2h(v1.x); o[5]=f2h(v1.y); o[6]=f2h(v1.z); o[7]=f2h(v1.w);
    *(us8*)(Wcat + (long)mat * 589824 + base) = o;
  } else {
    int t = (bid - 13248) * 256 + threadIdx.x;   // 4096 = 128 pos x 32 freq
    int p = t >> 5, i = t & 31;
    double ang = (double)p * pow(10000.0, -(double)i / 32.0);
    rope[2*t]   = (float)cos(ang);
    rope[2*t+1] = (float)sin(ang);
  }
}

// ================= fused QKV GEMM (+bias +RoPE epilogue) =================
// Y[M][2304] = X[M][768] @ Wcat[2304][768]^T ; 128x128 tile, BK=64, 4 waves.
// 2-phase double-buffer with counted vmcnt (T3/T4) + XCD-chunked nt-fastest order (T1).
__global__ __launch_bounds__(256) void qkv_gemm(
    const unsigned short* __restrict__ Xb, const unsigned short* __restrict__ Wb,
    const float* __restrict__ bqp, const float* __restrict__ bkp, const float* __restrict__ bvp,
    const float* __restrict__ rope, unsigned short* __restrict__ QKV)
{
  __shared__ __align__(16) unsigned char ldsA[2][16384];  // 128 rows x 64 f16 (128B), swizzled
  __shared__ __align__(16) unsigned char ldsB[2][16384];
  const int tid = threadIdx.x, lane = tid & 63, wid = tid >> 6;

  // bijective XCD-chunk remap (m204) so each XCD owns a contiguous wgid range,
  // then nt-fastest so consecutive wgids share one A-tile (A read ~once from HBM).
  const int bid0 = blockIdx.x;
  const int xcd = bid0 & 7, idx = bid0 >> 3;
  const int wgid = (xcd < XR8 ? xcd * (XQ8 + 1) : XR8 * (XQ8 + 1) + (xcd - XR8) * XQ8) + idx;
  const int mt = wgid / 18;
  const int nt = wgid % 18;
  const long m0 = (long)mt * 128;
  const int  n0 = nt * 128;
  const int wm = wid >> 1, wn = wid & 1;

  f4 acc[4][4];
  #pragma unroll
  for (int i = 0; i < 4; ++i)
    #pragma unroll
    for (int j = 0; j < 4; ++j) acc[i][j] = f4z();

  const char* Xc = (const char*)Xb;
  const char* Wc = (const char*)Wb;

#define STAGE(Abuf, Bbuf, kt) do {                                          \
    const int k0b_ = (kt) * 128;                                            \
    _Pragma("unroll")                                                       \
    for (int i_ = 0; i_ < 4; ++i_) {                                        \
      const int ob_ = ((i_ << 2) + wid) * 1024;  /* wave-uniform base */    \
      const int o_  = ob_ + lane * 16;           /* linear dest byte */     \
      const int row_ = o_ >> 7, cb_ = o_ & 127;                             \
      const int csrc_ = cb_ ^ ((row_ & 7) << 4); /* pre-swizzled src */     \
      GLL16(Xc + (m0 + row_) * 1536 + k0b_ + csrc_, (Abuf) + ob_);          \
      GLL16(Wc + (long)(n0 + row_) * 1536 + k0b_ + csrc_, (Bbuf) + ob_);    \
    }                                                                       \
  } while (0)

#define COMPUTE(Abuf, Bbuf) do {                                            \
    _Pragma("unroll")                                                       \
    for (int ks_ = 0; ks_ < 2; ++ks_) {                                     \
      h8 a_[4], b_[4];                                                      \
      const int kb_ = ks_ * 64 + ((lane >> 4) << 4);                        \
      _Pragma("unroll")                                                     \
      for (int f_ = 0; f_ < 4; ++f_) {                                      \
        const int ra_ = wm * 64 + f_ * 16 + (lane & 15);                    \
        a_[f_] = *(const h8*)((Abuf) + ra_ * 128 + (kb_ ^ ((ra_ & 7) << 4)));\
        const int rb_ = wn * 64 + f_ * 16 + (lane & 15);                    \
        b_[f_] = *(const h8*)((Bbuf) + rb_ * 128 + (kb_ ^ ((rb_ & 7) << 4)));\
      }                                                                     \
      _Pragma("unroll")                                                     \
      for (int fm_ = 0; fm_ < 4; ++fm_)                                     \
        _Pragma("unroll")                                                   \
        for (int fn_ = 0; fn_ < 4; ++fn_)                                   \
          acc[fm_][fn_] = MFMA16(a_[fm_], b_[fn_], acc[fm_][fn_]);          \
    }                                                                       \
  } while (0)

  unsigned char* A0 = ldsA[0];  unsigned char* A1 = ldsA[1];
  unsigned char* B0 = ldsB[0];  unsigned char* B1 = ldsB[1];

  STAGE(A0, B0, 0);                       // prologue: 8 loads in flight
  #pragma unroll
  for (int kt = 0; kt < 12; kt += 2) {
    STAGE(A1, B1, kt + 1);                             // prefetch odd tile
    asm volatile("s_waitcnt vmcnt(8)" ::: "memory");   // even tile landed
    __builtin_amdgcn_s_barrier();
    asm volatile("" ::: "memory");
    COMPUTE(A0, B0);
    asm volatile("" ::: "memory");
    __builtin_amdgcn_s_barrier();                      // all waves done reading buf0
    if (kt + 2 < 12) {
      STAGE(A0, B0, kt + 2);                           // prefetch next even tile
      asm volatile("s_waitcnt vmcnt(8)" ::: "memory"); // odd tile landed
    } else {
      asm volatile("s_waitcnt vmcnt(0)" ::: "memory");
    }
    __builtin_amdgcn_s_barrier();
    asm volatile("" ::: "memory");
    COMPUTE(A1, B1);
    asm volatile("" ::: "memory");
    __builtin_amdgcn_s_barrier();                      // all waves done reading buf1
  }
#undef STAGE
#undef COMPUTE

  // epilogue: bias + RoPE (wave spans exactly one head: 64 cols) + f16 store
  const int colb = n0 + wn * 64;
  const int sel = (colb >= 1536) ? 2 : (colb >= 768) ? 1 : 0;
  const float* bias = (sel == 0) ? bqp : (sel == 1) ? bkp : bvp;
  const int hcol = colb % 768;
  float bia[4];
  #pragma unroll
  for (int f = 0; f < 4; ++f) bia[f] = bias[hcol + f * 16 + (lane & 15)];

  #pragma unroll
  for (int fm = 0; fm < 4; ++fm) {
    #pragma unroll
    for (int reg = 0; reg < 4; ++reg) {
      const long m = m0 + wm * 64 + fm * 16 + ((lane >> 4) << 2) + reg;
      const int s = (int)(m % (long)S);
      const int pos = (s < 64) ? s : ((s - 64) & 127);
      unsigned short* orow = QKV + m * N3 + colb;
      if (sel < 2) {  // Q or K: rotate (d, d+32) pairs = (fn, fn+2) same lane
        #pragma unroll
        for (int f = 0; f < 2; ++f) {
          const int d1 = f * 16 + (lane & 15);
          const float c  = rope[(pos * 32 + d1) * 2];
          const float sn = rope[(pos * 32 + d1) * 2 + 1];
          const float x1 = acc[fm][f][reg]     + bia[f];
          const float x2 = acc[fm][f + 2][reg] + bia[f + 2];
          orow[f * 16 + (lane & 15)]       = f2h(x1 * c - x2 * sn);
          orow[(f + 2) * 16 + (lane & 15)] = f2h(x2 * c + x1 * sn);
        }
      } else {        // V: bias only
        #pragma unroll
        for (int f = 0; f < 4; ++f)
          orow[f * 16 + (lane & 15)] = f2h(acc[fm][f][reg] + bia[f]);
      }
    }
  }
}

// ================= attention (one block per (b, window, head)) =================
// T=128 local windows, T=64 global head block. 4 waves; wave owns 32 Q rows.
template <int T>
__global__ __launch_bounds__(256) void attn_kernel(
    const unsigned short* __restrict__ QKV, float* __restrict__ out)
{
  constexpr int NF  = T / 16;   // col fragments of scores
  constexpr int NKS = T / 32;   // k-steps of PV
  __shared__ __align__(16) unsigned char sVT[16384];   // V^T [64 d][128 j] f16, chunk^=(d&15)
  __shared__ __align__(16) unsigned char sP[4][8192];  // per-wave P [32][128] f16, swizzled

  const int tid = threadIdx.x, lane = tid & 63, w = tid >> 6;
  int bid = blockIdx.x;
  const int h = bid % NH; bid /= NH;
  long row0;
  if (T == 64) row0 = (long)bid * S;
  else { const int ww = bid % 64; const int b = bid / 64; row0 = (long)b * S + 64 + (long)ww * 128; }
  const unsigned short* Qb = QKV + row0 * N3 + h * HD;
  const unsigned short* Kb = Qb + H;
  const unsigned short* Vb = Qb + 2 * H;

  // ---- stage V^T: wave = 16-d chunk, lane = token pair (conflict-free b32 writes) ----
  {
    const int p = lane;
    if (2 * p + 1 < T) {
      const unsigned short* v0 = Vb + (long)(2 * p) * N3 + w * 16;
      const unsigned short* v1 = v0 + N3;
      us8 a0 = *(const us8*)(v0);
      us8 a1 = *(const us8*)(v0 + 8);
      us8 c0 = *(const us8*)(v1);
      us8 c1 = *(const us8*)(v1 + 8);
      #pragma unroll
      for (int i = 0; i < 8; ++i) {
        const int d = w * 16 + i, d2 = d + 8;
        *(unsigned*)(sVT + d  * 256 + ((4 * p) ^ ((d  & 15) << 4))) = (unsigned)a0[i] | ((unsigned)c0[i] << 16);
        *(unsigned*)(sVT + d2 * 256 + ((4 * p) ^ ((d2 & 15) << 4))) = (unsigned)a1[i] | ((unsigned)c1[i] << 16);
      }
    }
  }
  __syncthreads();

  if (w * 32 < T) {
    // Q fragments straight from global (A-layout: m=lane&15, k=(lane>>4)*8)
    h8 aq[2][2];
    #pragma unroll
    for (int fm = 0; fm < 2; ++fm)
      #pragma unroll
      for (int ks = 0; ks < 2; ++ks) {
        const long r = w * 32 + fm * 16 + (lane & 15);
        aq[fm][ks] = *(const h8*)(Qb + r * N3 + ks * 32 + ((lane >> 4) << 3));
      }

    // ---- S = Q K^T (K B-frags from global) ----
    f4 acc[2][NF];
    #pragma unroll
    for (int i = 0; i < 2; ++i)
      #pragma unroll
      for (int f = 0; f < NF; ++f) acc[i][f] = f4z();

    #pragma unroll
    for (int f = 0; f < NF; ++f) {
      const long rk = f * 16 + (lane & 15);
      const unsigned short* kr = Kb + rk * N3 + ((lane >> 4) << 3);
      h8 b0 = *(const h8*)(kr);
      h8 b1 = *(const h8*)(kr + 32);
      acc[0][f] = MFMA16(aq[0][0], b0, acc[0][f]);
      acc[0][f] = MFMA16(aq[0][1], b1, acc[0][f]);
      acc[1][f] = MFMA16(aq[1][0], b0, acc[1][f]);
      acc[1][f] = MFMA16(aq[1][1], b1, acc[1][f]);
    }

    // ---- softmax over keys; write normalized P (f16) to per-wave LDS ----
    unsigned char* Pw = sP[w];
    #pragma unroll
    for (int fm = 0; fm < 2; ++fm) {
      #pragma unroll
      for (int reg = 0; reg < 4; ++reg) {
        float mx = -3.0e38f;
        #pragma unroll
        for (int f = 0; f < NF; ++f) mx = fmaxf(mx, acc[fm][f][reg]);
        mx = fmaxf(mx, __shfl_xor(mx, 1));
        mx = fmaxf(mx, __shfl_xor(mx, 2));
        mx = fmaxf(mx, __shfl_xor(mx, 4));
        mx = fmaxf(mx, __shfl_xor(mx, 8));
        float pv[NF], sum = 0.f;
        #pragma unroll
        for (int f = 0; f < NF; ++f) {
          const float p = __expf((acc[fm][f][reg] - mx) * 0.125f);  // /sqrt(64) folded in
          pv[f] = p; sum += p;
        }
        sum += __shfl_xor(sum, 1);
        sum += __shfl_xor(sum, 2);
        sum += __shfl_xor(sum, 4);
        sum += __shfl_xor(sum, 8);
        const float inv = 1.0f / sum;
        const int rloc = fm * 16 + ((lane >> 4) << 2) + reg;
        const int swz = (rloc & 7) << 4;
        #pragma unroll
        for (int f = 0; f < NF; ++f) {
          const int cb = (f * 16 + (lane & 15)) * 2;
          *(unsigned short*)(Pw + rloc * 256 + (cb ^ swz)) = f2h(pv[f] * inv);
        }
      }
    }

    // ---- ctx = P V ----
    f4 acc2[2][4];
    #pragma unroll
    for (int i = 0; i < 2; ++i)
      #pragma unroll
      for (int j = 0; j < 4; ++j) acc2[i][j] = f4z();

    #pragma unroll
    for (int ks = 0; ks < NKS; ++ks) {
      h8 pa[2], vb[4];
      const int kb = ks * 64 + ((lane >> 4) << 4);
      #pragma unroll
      for (int fm = 0; fm < 2; ++fm) {
        const int rp = fm * 16 + (lane & 15);
        pa[fm] = *(const h8*)(Pw + rp * 256 + (kb ^ ((rp & 7) << 4)));
      }
      #pragma unroll
      for (int df = 0; df < 4; ++df) {
        const int d = df * 16 + (lane & 15);
        vb[df] = *(const h8*)(sVT + d * 256 + (kb ^ ((d & 15) << 4)));
      }
      #pragma unroll
      for (int fm = 0; fm < 2; ++fm)
        #pragma unroll
        for (int df = 0; df < 4; ++df)
          acc2[fm][df] = MFMA16(pa[fm], vb[df], acc2[fm][df]);
    }

    // ---- write ctx fp32 to [B][S][H] ----
    float* ob = out + (row0 + w * 32) * H + h * HD;
    #pragma unroll
    for (int fm = 0; fm < 2; ++fm)
      #pragma unroll
      for (int df = 0; df < 4; ++df)
        #pragma unroll
        for (int reg = 0; reg < 4; ++reg) {
          const long r = fm * 16 + ((lane >> 4) << 2) + reg;
          const int c = df * 16 + (lane & 15);
          ob[r * H + c] = acc2[fm][df][reg];
        }
  }
}

// ================= launcher =================
extern "C" void kernel_launch(void* const* d_in, const int* in_sizes, int n_in,
                              void* d_out, int out_size, void* d_ws, size_t ws_size,
                              hipStream_t stream) {
  const float* X  = (const float*)d_in[0];
  // d_in[1] = attention_mask (unused by the reference math)
  const float* Wq = (const float*)d_in[2];
  const float* bq = (const float*)d_in[3];
  const float* Wk = (const float*)d_in[4];
  const float* bk = (const float*)d_in[5];
  const float* Wv = (const float*)d_in[6];
  const float* bv = (const float*)d_in[7];
  float* out = (float*)d_out;

  if ((long)ws_size < WS_NEEDED) return;  // clean fail if scratch too small

  char* ws = (char*)d_ws;
  unsigned short* Xb   = (unsigned short*)(ws + XB_OFF);
  unsigned short* Wcat = (unsigned short*)(ws + W_OFF);
  float*          rope = (float*)(ws + ROPE_OFF);
  unsigned short* QKV  = (unsigned short*)(ws + QKV_OFF);

  prep_kernel<<<13264, 256, 0, stream>>>(X, Wq, Wk, Wv, Xb, Wcat, rope);
  qkv_gemm<<<NWG_GEMM, 256, 0, stream>>>(Xb, Wcat, bq, bk, bv, rope, QKV);
  attn_kernel<64><<<B * NH, 256, 0, stream>>>(QKV, out);
  attn_kernel<128><<<B * 64 * NH, 256, 0, stream>>>(QKV, out);
}

// Round 7
// 412.172 us; speedup vs baseline: 1.1369x; 1.0140x over previous
//
#include <hip/hip_runtime.h>
#include <stdint.h>

// ---------------- problem constants ----------------
constexpr int B  = 4, S = 8256, H = 768, NH = 12, HD = 64;
constexpr int M  = B * S;        // 33024 rows
constexpr int N3 = 3 * H;        // 2304 fused QKV cols
// GEMM tiling: 256x256, BK=64, 8 waves (512 thr)
constexpr int MT = M / 256;      // 129
constexpr int NT = N3 / 256;     // 9
constexpr int NWG_GEMM = MT * NT;                 // 1161
constexpr int XQ8 = NWG_GEMM / 8, XR8 = NWG_GEMM % 8;  // 145, 1
// workspace layout (bytes)
constexpr long XB_OFF   = 0;
constexpr long XB_BYTES = (long)M * H * 2;        // 50,724,864  f16 X
constexpr long W_OFF    = XB_OFF + XB_BYTES;
constexpr long W_BYTES  = (long)N3 * H * 2;       // 3,538,944   f16 Wq|Wk|Wv
constexpr long ROPE_OFF = W_OFF + W_BYTES;
constexpr long ROPE_BYTES = 128 * 32 * 2 * 4;     // 32 KB cos/sin table
constexpr long QKV_OFF  = ROPE_OFF + ROPE_BYTES;
constexpr long QKV_BYTES = (long)M * N3 * 2;      // 152,174,592 f16 QKV (rope applied)
constexpr long WS_NEEDED = QKV_OFF + QKV_BYTES;   // ~197 MB

typedef __attribute__((ext_vector_type(8))) _Float16 h8;        // 8 f16 = 4 VGPR (MFMA operand)
typedef __attribute__((ext_vector_type(8))) unsigned short us8;
typedef __attribute__((ext_vector_type(4))) float f4;

#define MFMA16(a,b,c) __builtin_amdgcn_mfma_f32_16x16x32_f16((a),(b),(c),0,0,0)
#define GLL16(gp, lp) __builtin_amdgcn_global_load_lds( \
    (__attribute__((address_space(1))) void*)(gp),      \
    (__attribute__((address_space(3))) void*)(lp), 16, 0, 0)

static __device__ __forceinline__ unsigned short f2h(float x) {  // RNE f32->f16
  _Float16 h = (_Float16)x;
  return __builtin_bit_cast(unsigned short, h);
}
static __device__ __forceinline__ f4 f4z() { f4 z = {0.f,0.f,0.f,0.f}; return z; }

// ================= prep: fp32->f16 converts + rope table =================
// blocks [0,12384): X   | [12384,13248): Wq/Wk/Wv | [13248,13264): rope table
__global__ __launch_bounds__(256) void prep_kernel(
    const float* __restrict__ X,
    const float* __restrict__ Wq, const float* __restrict__ Wk, const float* __restrict__ Wv,
    unsigned short* __restrict__ Xb, unsigned short* __restrict__ Wcat, float* __restrict__ rope)
{
  int bid = blockIdx.x;
  if (bid < 12384) {
    long base = (long)bid * 2048 + threadIdx.x * 8;
    float4 v0 = *(const float4*)(X + base);
    float4 v1 = *(const float4*)(X + base + 4);
    us8 o;
    o[0]=f2h(v0.x); o[1]=f2h(v0.y); o[2]=f2h(v0.z); o[3]=f2h(v0.w);
    o[4]=f2h(v1.x); o[5]=f2h(v1.y); o[6]=f2h(v1.z); o[7]=f2h(v1.w);
    *(us8*)(Xb + base) = o;
  } else if (bid < 13248) {
    int wb  = bid - 12384;
    int mat = wb / 288;
    int base = (wb % 288) * 2048 + threadIdx.x * 8;
    const float* src = (mat == 0) ? Wq : (mat == 1) ? Wk : Wv;
    float4 v0 = *(const float4*)(src + base);
    float4 v1 = *(const float4*)(src + base + 4);
    us8 o;
    o[0]=f2h(v0.x); o[1]=f2h(v0.y); o[2]=f2h(v0.z); o[3]=f2h(v0.w);
    o[4]=f2h(v1.x); o[5]=f2h(v1.y); o[6]=f2h(v1.z); o[7]=f2h(v1.w);
    *(us8*)(Wcat + (long)mat * 589824 + base) = o;
  } else {
    int t = (bid - 13248) * 256 + threadIdx.x;   // 4096 = 128 pos x 32 freq
    int p = t >> 5, i = t & 31;
    double ang = (double)p * pow(10000.0, -(double)i / 32.0);
    rope[2*t]   = (float)cos(ang);
    rope[2*t+1] = (float)sin(ang);
  }
}

// ================= fused QKV GEMM (+bias +RoPE epilogue) =================
// Y[M][2304] = X[M][768] @ Wcat[2304][768]^T ; 256x256 tile, BK=64, 8 waves.
// 2-phase double-buffer, counted vmcnt (T3/T4). nt-major XCD chunking: each
// XCD owns ~1.1 B-panels (L2-resident); all XCDs sweep mt in parallel so A is
// served once from HBM via L3.
__global__ __launch_bounds__(512, 2) void qkv_gemm(
    const unsigned short* __restrict__ Xb, const unsigned short* __restrict__ Wb,
    const float* __restrict__ bqp, const float* __restrict__ bkp, const float* __restrict__ bvp,
    const float* __restrict__ rope, unsigned short* __restrict__ QKV)
{
  // per buffer 64KB: A [256 rows][128B] swizzled at base 0, B same at +32768
  __shared__ __align__(16) unsigned char lds[2][65536];
  const int tid = threadIdx.x, lane = tid & 63, wid = tid >> 6;

  // bijective XCD-chunk remap (m204), nt-major within chunk
  const int bid0 = blockIdx.x;
  const int xcd = bid0 & 7, idx = bid0 >> 3;
  const int wgid = (xcd < XR8 ? xcd * (XQ8 + 1) : XR8 * (XQ8 + 1) + (xcd - XR8) * XQ8) + idx;
  const int nt = wgid / MT;
  const int mt = wgid % MT;
  const long m0 = (long)mt * 256;
  const int  n0 = nt * 256;
  const int wm = wid >> 2, wn = wid & 3;   // 2M x 4N waves of 128x64 output

  f4 acc[8][4];
  #pragma unroll
  for (int i = 0; i < 8; ++i)
    #pragma unroll
    for (int j = 0; j < 4; ++j) acc[i][j] = f4z();

  const char* Xc = (const char*)Xb;
  const char* Wc = (const char*)Wb;

#define STAGE(buf, kt) do {                                                 \
    const int k0b_ = (kt) * 128;                                            \
    _Pragma("unroll")                                                       \
    for (int i_ = 0; i_ < 8; ++i_) {                                        \
      const int ob_ = i_ * 8192 + wid * 1024;   /* wave-uniform base */     \
      const int o_  = ob_ + lane * 16;          /* linear dest byte */      \
      if (i_ < 4) {                              /* A region [0,32768) */   \
        const int row_ = o_ >> 7, cb_ = o_ & 127;                           \
        const int csrc_ = cb_ ^ ((row_ & 7) << 4);                          \
        GLL16(Xc + (m0 + row_) * 1536 + k0b_ + csrc_, (buf) + ob_);         \
      } else {                                   /* B region [32768,64K) */ \
        const int o2_ = o_ - 32768;                                         \
        const int row_ = o2_ >> 7, cb_ = o2_ & 127;                         \
        const int csrc_ = cb_ ^ ((row_ & 7) << 4);                          \
        GLL16(Wc + (long)(n0 + row_) * 1536 + k0b_ + csrc_, (buf) + ob_);   \
      }                                                                     \
    }                                                                       \
  } while (0)

#define COMPUTE(buf) do {                                                   \
    _Pragma("unroll")                                                       \
    for (int ks_ = 0; ks_ < 2; ++ks_) {                                     \
      h8 a_[8], b_[4];                                                      \
      const int kb_ = ks_ * 64 + ((lane >> 4) << 4);                        \
      _Pragma("unroll")                                                     \
      for (int f_ = 0; f_ < 8; ++f_) {                                      \
        const int ra_ = wm * 128 + f_ * 16 + (lane & 15);                   \
        a_[f_] = *(const h8*)((buf) + ra_ * 128 + (kb_ ^ ((ra_ & 7) << 4)));\
      }                                                                     \
      _Pragma("unroll")                                                     \
      for (int f_ = 0; f_ < 4; ++f_) {                                      \
        const int rb_ = wn * 64 + f_ * 16 + (lane & 15);                    \
        b_[f_] = *(const h8*)((buf) + 32768 + rb_ * 128 + (kb_ ^ ((rb_ & 7) << 4))); \
      }                                                                     \
      _Pragma("unroll")                                                     \
      for (int fm_ = 0; fm_ < 8; ++fm_)                                     \
        _Pragma("unroll")                                                   \
        for (int fn_ = 0; fn_ < 4; ++fn_)                                   \
          acc[fm_][fn_] = MFMA16(a_[fm_], b_[fn_], acc[fm_][fn_]);          \
    }                                                                       \
  } while (0)

  unsigned char* L0 = lds[0];
  unsigned char* L1 = lds[1];

  STAGE(L0, 0);                            // prologue: 8 loads in flight
  #pragma unroll
  for (int kt = 0; kt < 12; kt += 2) {
    STAGE(L1, kt + 1);                                 // prefetch odd tile
    asm volatile("s_waitcnt vmcnt(8)" ::: "memory");   // even tile landed
    __builtin_amdgcn_s_barrier();
    asm volatile("" ::: "memory");
    COMPUTE(L0);
    asm volatile("" ::: "memory");
    __builtin_amdgcn_s_barrier();                      // all waves done reading buf0
    if (kt + 2 < 12) {
      STAGE(L0, kt + 2);                               // prefetch next even tile
      asm volatile("s_waitcnt vmcnt(8)" ::: "memory"); // odd tile landed
    } else {
      asm volatile("s_waitcnt vmcnt(0)" ::: "memory");
    }
    __builtin_amdgcn_s_barrier();
    asm volatile("" ::: "memory");
    COMPUTE(L1);
    asm volatile("" ::: "memory");
    __builtin_amdgcn_s_barrier();                      // all waves done reading buf1
  }
#undef STAGE
#undef COMPUTE

  // epilogue: bias + RoPE (wave spans exactly one head: 64 cols) + f16 store
  const int colb = n0 + wn * 64;
  const int sel = (colb >= 1536) ? 2 : (colb >= 768) ? 1 : 0;
  const float* bias = (sel == 0) ? bqp : (sel == 1) ? bkp : bvp;
  const int hcol = colb % 768;
  float bia[4];
  #pragma unroll
  for (int f = 0; f < 4; ++f) bia[f] = bias[hcol + f * 16 + (lane & 15)];

  #pragma unroll
  for (int fm = 0; fm < 8; ++fm) {
    #pragma unroll
    for (int reg = 0; reg < 4; ++reg) {
      const long m = m0 + wm * 128 + fm * 16 + ((lane >> 4) << 2) + reg;
      const int s = (int)(m % (long)S);
      const int pos = (s < 64) ? s : ((s - 64) & 127);
      unsigned short* orow = QKV + m * N3 + colb;
      if (sel < 2) {  // Q or K: rotate (d, d+32) pairs = (fn, fn+2) same lane
        #pragma unroll
        for (int f = 0; f < 2; ++f) {
          const int d1 = f * 16 + (lane & 15);
          const float c  = rope[(pos * 32 + d1) * 2];
          const float sn = rope[(pos * 32 + d1) * 2 + 1];
          const float x1 = acc[fm][f][reg]     + bia[f];
          const float x2 = acc[fm][f + 2][reg] + bia[f + 2];
          orow[f * 16 + (lane & 15)]       = f2h(x1 * c - x2 * sn);
          orow[(f + 2) * 16 + (lane & 15)] = f2h(x2 * c + x1 * sn);
        }
      } else {        // V: bias only
        #pragma unroll
        for (int f = 0; f < 4; ++f)
          orow[f * 16 + (lane & 15)] = f2h(acc[fm][f][reg] + bia[f]);
      }
    }
  }
}

// ================= attention (one block per (b, window, head)) =================
// T=128 local windows, T=64 global head block. 4 waves; wave owns 32 Q rows.
template <int T>
__global__ __launch_bounds__(256) void attn_kernel(
    const unsigned short* __restrict__ QKV, float* __restrict__ out)
{
  constexpr int NF  = T / 16;   // col fragments of scores
  constexpr int NKS = T / 32;   // k-steps of PV
  __shared__ __align__(16) unsigned char sVT[16384];   // V^T [64 d][128 j] f16, chunk^=(d&15)
  __shared__ __align__(16) unsigned char sP[4][8192];  // per-wave P [32][128] f16, swizzled

  const int tid = threadIdx.x, lane = tid & 63, w = tid >> 6;
  int bid = blockIdx.x;
  const int h = bid % NH; bid /= NH;
  long row0;
  if (T == 64) row0 = (long)bid * S;
  else { const int ww = bid % 64; const int b = bid / 64; row0 = (long)b * S + 64 + (long)ww * 128; }
  const unsigned short* Qb = QKV + row0 * N3 + h * HD;
  const unsigned short* Kb = Qb + H;
  const unsigned short* Vb = Qb + 2 * H;

  // ---- stage V^T: wave = 16-d chunk, lane = token pair (conflict-free b32 writes) ----
  {
    const int p = lane;
    if (2 * p + 1 < T) {
      const unsigned short* v0 = Vb + (long)(2 * p) * N3 + w * 16;
      const unsigned short* v1 = v0 + N3;
      us8 a0 = *(const us8*)(v0);
      us8 a1 = *(const us8*)(v0 + 8);
      us8 c0 = *(const us8*)(v1);
      us8 c1 = *(const us8*)(v1 + 8);
      #pragma unroll
      for (int i = 0; i < 8; ++i) {
        const int d = w * 16 + i, d2 = d + 8;
        *(unsigned*)(sVT + d  * 256 + ((4 * p) ^ ((d  & 15) << 4))) = (unsigned)a0[i] | ((unsigned)c0[i] << 16);
        *(unsigned*)(sVT + d2 * 256 + ((4 * p) ^ ((d2 & 15) << 4))) = (unsigned)a1[i] | ((unsigned)c1[i] << 16);
      }
    }
  }
  __syncthreads();

  if (w * 32 < T) {
    // Q fragments straight from global (A-layout: m=lane&15, k=(lane>>4)*8)
    h8 aq[2][2];
    #pragma unroll
    for (int fm = 0; fm < 2; ++fm)
      #pragma unroll
      for (int ks = 0; ks < 2; ++ks) {
        const long r = w * 32 + fm * 16 + (lane & 15);
        aq[fm][ks] = *(const h8*)(Qb + r * N3 + ks * 32 + ((lane >> 4) << 3));
      }

    // ---- S = Q K^T (K B-frags from global) ----
    f4 acc[2][NF];
    #pragma unroll
    for (int i = 0; i < 2; ++i)
      #pragma unroll
      for (int f = 0; f < NF; ++f) acc[i][f] = f4z();

    #pragma unroll
    for (int f = 0; f < NF; ++f) {
      const long rk = f * 16 + (lane & 15);
      const unsigned short* kr = Kb + rk * N3 + ((lane >> 4) << 3);
      h8 b0 = *(const h8*)(kr);
      h8 b1 = *(const h8*)(kr + 32);
      acc[0][f] = MFMA16(aq[0][0], b0, acc[0][f]);
      acc[0][f] = MFMA16(aq[0][1], b1, acc[0][f]);
      acc[1][f] = MFMA16(aq[1][0], b0, acc[1][f]);
      acc[1][f] = MFMA16(aq[1][1], b1, acc[1][f]);
    }

    // ---- softmax over keys; write normalized P (f16) to per-wave LDS ----
    unsigned char* Pw = sP[w];
    #pragma unroll
    for (int fm = 0; fm < 2; ++fm) {
      #pragma unroll
      for (int reg = 0; reg < 4; ++reg) {
        float mx = -3.0e38f;
        #pragma unroll
        for (int f = 0; f < NF; ++f) mx = fmaxf(mx, acc[fm][f][reg]);
        mx = fmaxf(mx, __shfl_xor(mx, 1));
        mx = fmaxf(mx, __shfl_xor(mx, 2));
        mx = fmaxf(mx, __shfl_xor(mx, 4));
        mx = fmaxf(mx, __shfl_xor(mx, 8));
        float pv[NF], sum = 0.f;
        #pragma unroll
        for (int f = 0; f < NF; ++f) {
          const float p = __expf((acc[fm][f][reg] - mx) * 0.125f);  // /sqrt(64) folded in
          pv[f] = p; sum += p;
        }
        sum += __shfl_xor(sum, 1);
        sum += __shfl_xor(sum, 2);
        sum += __shfl_xor(sum, 4);
        sum += __shfl_xor(sum, 8);
        const float inv = 1.0f / sum;
        const int rloc = fm * 16 + ((lane >> 4) << 2) + reg;
        const int swz = (rloc & 7) << 4;
        #pragma unroll
        for (int f = 0; f < NF; ++f) {
          const int cb = (f * 16 + (lane & 15)) * 2;
          *(unsigned short*)(Pw + rloc * 256 + (cb ^ swz)) = f2h(pv[f] * inv);
        }
      }
    }

    // ---- ctx = P V ----
    f4 acc2[2][4];
    #pragma unroll
    for (int i = 0; i < 2; ++i)
      #pragma unroll
      for (int j = 0; j < 4; ++j) acc2[i][j] = f4z();

    #pragma unroll
    for (int ks = 0; ks < NKS; ++ks) {
      h8 pa[2], vb[4];
      const int kb = ks * 64 + ((lane >> 4) << 4);
      #pragma unroll
      for (int fm = 0; fm < 2; ++fm) {
        const int rp = fm * 16 + (lane & 15);
        pa[fm] = *(const h8*)(Pw + rp * 256 + (kb ^ ((rp & 7) << 4)));
      }
      #pragma unroll
      for (int df = 0; df < 4; ++df) {
        const int d = df * 16 + (lane & 15);
        vb[df] = *(const h8*)(sVT + d * 256 + (kb ^ ((d & 15) << 4)));
      }
      #pragma unroll
      for (int fm = 0; fm < 2; ++fm)
        #pragma unroll
        for (int df = 0; df < 4; ++df)
          acc2[fm][df] = MFMA16(pa[fm], vb[df], acc2[fm][df]);
    }

    // ---- write ctx fp32 to [B][S][H] ----
    float* ob = out + (row0 + w * 32) * H + h * HD;
    #pragma unroll
    for (int fm = 0; fm < 2; ++fm)
      #pragma unroll
      for (int df = 0; df < 4; ++df)
        #pragma unroll
        for (int reg = 0; reg < 4; ++reg) {
          const long r = fm * 16 + ((lane >> 4) << 2) + reg;
          const int c = df * 16 + (lane & 15);
          ob[r * H + c] = acc2[fm][df][reg];
        }
  }
}

// ================= launcher =================
extern "C" void kernel_launch(void* const* d_in, const int* in_sizes, int n_in,
                              void* d_out, int out_size, void* d_ws, size_t ws_size,
                              hipStream_t stream) {
  const float* X  = (const float*)d_in[0];
  // d_in[1] = attention_mask (unused by the reference math)
  const float* Wq = (const float*)d_in[2];
  const float* bq = (const float*)d_in[3];
  const float* Wk = (const float*)d_in[4];
  const float* bk = (const float*)d_in[5];
  const float* Wv = (const float*)d_in[6];
  const float* bv = (const float*)d_in[7];
  float* out = (float*)d_out;

  if ((long)ws_size < WS_NEEDED) return;  // clean fail if scratch too small

  char* ws = (char*)d_ws;
  unsigned short* Xb   = (unsigned short*)(ws + XB_OFF);
  unsigned short* Wcat = (unsigned short*)(ws + W_OFF);
  float*          rope = (float*)(ws + ROPE_OFF);
  unsigned short* QKV  = (unsigned short*)(ws + QKV_OFF);

  prep_kernel<<<13264, 256, 0, stream>>>(X, Wq, Wk, Wv, Xb, Wcat, rope);
  qkv_gemm<<<NWG_GEMM, 512, 0, stream>>>(Xb, Wcat, bq, bk, bv, rope, QKV);
  attn_kernel<64><<<B * NH, 256, 0, stream>>>(QKV, out);
  attn_kernel<128><<<B * 64 * NH, 256, 0, stream>>>(QKV, out);
}

// Round 10
// 399.927 us; speedup vs baseline: 1.1717x; 1.0306x over previous
//
#include <hip/hip_runtime.h>
#include <stdint.h>

// ---------------- problem constants ----------------
constexpr int B  = 4, S = 8256, H = 768, NH = 12, HD = 64;
constexpr int M  = B * S;        // 33024 rows
constexpr int N3 = 3 * H;        // 2304 fused QKV cols
constexpr int NWG_GEMM = (M / 128) * (N3 / 128);   // 4644
constexpr int XQ8 = NWG_GEMM / 8, XR8 = NWG_GEMM % 8;
// workspace layout (bytes)
constexpr long XB_OFF   = 0;
constexpr long XB_BYTES = (long)M * H * 2;        // 50,724,864  f16 X
constexpr long W_OFF    = XB_OFF + XB_BYTES;
constexpr long W_BYTES  = (long)N3 * H * 2;       // 3,538,944   f16 Wq|Wk|Wv
constexpr long ROPE_OFF = W_OFF + W_BYTES;
constexpr long ROPE_BYTES = 128 * 32 * 2 * 4;     // 32 KB cos/sin table
constexpr long QKV_OFF  = ROPE_OFF + ROPE_BYTES;
constexpr long QKV_BYTES = (long)M * N3 * 2;      // 152,174,592 f16 QKV (rope applied)
constexpr long WS_NEEDED = QKV_OFF + QKV_BYTES;   // ~197 MB

typedef __attribute__((ext_vector_type(8))) _Float16 h8;        // 8 f16 = 4 VGPR (MFMA operand)
typedef __attribute__((ext_vector_type(8))) unsigned short us8;
typedef __attribute__((ext_vector_type(4))) float f4;

#define MFMA16(a,b,c) __builtin_amdgcn_mfma_f32_16x16x32_f16((a),(b),(c),0,0,0)
#define GLL16(gp, lp) __builtin_amdgcn_global_load_lds( \
    (__attribute__((address_space(1))) void*)(gp),      \
    (__attribute__((address_space(3))) void*)(lp), 16, 0, 0)

static __device__ __forceinline__ unsigned short f2h(float x) {  // RNE f32->f16
  _Float16 h = (_Float16)x;
  return __builtin_bit_cast(unsigned short, h);
}
static __device__ __forceinline__ f4 f4z() { f4 z = {0.f,0.f,0.f,0.f}; return z; }

// ================= prep: fp32->f16 converts + rope table =================
// blocks [0,12384): X   | [12384,13248): Wq/Wk/Wv | [13248,13264): rope table
__global__ __launch_bounds__(256) void prep_kernel(
    const float* __restrict__ X,
    const float* __restrict__ Wq, const float* __restrict__ Wk, const float* __restrict__ Wv,
    unsigned short* __restrict__ Xb, unsigned short* __restrict__ Wcat, float* __restrict__ rope)
{
  int bid = blockIdx.x;
  if (bid < 12384) {
    long base = (long)bid * 2048 + threadIdx.x * 8;
    float4 v0 = *(const float4*)(X + base);
    float4 v1 = *(const float4*)(X + base + 4);
    us8 o;
    o[0]=f2h(v0.x); o[1]=f2h(v0.y); o[2]=f2h(v0.z); o[3]=f2h(v0.w);
    o[4]=f2h(v1.x); o[5]=f2h(v1.y); o[6]=f2h(v1.z); o[7]=f2h(v1.w);
    *(us8*)(Xb + base) = o;
  } else if (bid < 13248) {
    int wb  = bid - 12384;
    int mat = wb / 288;
    int base = (wb % 288) * 2048 + threadIdx.x * 8;
    const float* src = (mat == 0) ? Wq : (mat == 1) ? Wk : Wv;
    float4 v0 = *(const float4*)(src + base);
    float4 v1 = *(const float4*)(src + base + 4);
    us8 o;
    o[0]=f2h(v0.x); o[1]=f2h(v0.y); o[2]=f2h(v0.z); o[3]=f2h(v0.w);
    o[4]=f2h(v1.x); o[5]=f2h(v1.y); o[6]=f2h(v1.z); o[7]=f2h(v1.w);
    *(us8*)(Wcat + (long)mat * 589824 + base) = o;
  } else {
    int t = (bid - 13248) * 256 + threadIdx.x;   // 4096 = 128 pos x 32 freq
    int p = t >> 5, i = t & 31;
    double ang = (double)p * pow(10000.0, -(double)i / 32.0);
    rope[2*t]   = (float)cos(ang);
    rope[2*t+1] = (float)sin(ang);
  }
}

// ================= fused QKV GEMM (+bias +RoPE epilogue) =================
// Y[M][2304] = X[M][768] @ Wcat[2304][768]^T ; 128x128 tile, BK=64, 4 waves.
// 2-phase double-buffer with counted vmcnt (T3/T4) + XCD-chunked nt-fastest order (T1).
// (round-6 proven config: 179 us, 2 blocks/CU)
__global__ __launch_bounds__(256) void qkv_gemm(
    const unsigned short* __restrict__ Xb, const unsigned short* __restrict__ Wb,
    const float* __restrict__ bqp, const float* __restrict__ bkp, const float* __restrict__ bvp,
    const float* __restrict__ rope, unsigned short* __restrict__ QKV)
{
  __shared__ __align__(16) unsigned char ldsA[2][16384];  // 128 rows x 64 f16 (128B), swizzled
  __shared__ __align__(16) unsigned char ldsB[2][16384];
  const int tid = threadIdx.x, lane = tid & 63, wid = tid >> 6;

  const int bid0 = blockIdx.x;
  const int xcd = bid0 & 7, idx = bid0 >> 3;
  const int wgid = (xcd < XR8 ? xcd * (XQ8 + 1) : XR8 * (XQ8 + 1) + (xcd - XR8) * XQ8) + idx;
  const int mt = wgid / 18;
  const int nt = wgid % 18;
  const long m0 = (long)mt * 128;
  const int  n0 = nt * 128;
  const int wm = wid >> 1, wn = wid & 1;

  f4 acc[4][4];
  #pragma unroll
  for (int i = 0; i < 4; ++i)
    #pragma unroll
    for (int j = 0; j < 4; ++j) acc[i][j] = f4z();

  const char* Xc = (const char*)Xb;
  const char* Wc = (const char*)Wb;

#define STAGE(Abuf, Bbuf, kt) do {                                          \
    const int k0b_ = (kt) * 128;                                            \
    _Pragma("unroll")                                                       \
    for (int i_ = 0; i_ < 4; ++i_) {                                        \
      const int ob_ = ((i_ << 2) + wid) * 1024;  /* wave-uniform base */    \
      const int o_  = ob_ + lane * 16;           /* linear dest byte */     \
      const int row_ = o_ >> 7, cb_ = o_ & 127;                             \
      const int csrc_ = cb_ ^ ((row_ & 7) << 4); /* pre-swizzled src */     \
      GLL16(Xc + (m0 + row_) * 1536 + k0b_ + csrc_, (Abuf) + ob_);          \
      GLL16(Wc + (long)(n0 + row_) * 1536 + k0b_ + csrc_, (Bbuf) + ob_);    \
    }                                                                       \
  } while (0)

#define COMPUTE(Abuf, Bbuf) do {                                            \
    _Pragma("unroll")                                                       \
    for (int ks_ = 0; ks_ < 2; ++ks_) {                                     \
      h8 a_[4], b_[4];                                                      \
      const int kb_ = ks_ * 64 + ((lane >> 4) << 4);                        \
      _Pragma("unroll")                                                     \
      for (int f_ = 0; f_ < 4; ++f_) {                                      \
        const int ra_ = wm * 64 + f_ * 16 + (lane & 15);                    \
        a_[f_] = *(const h8*)((Abuf) + ra_ * 128 + (kb_ ^ ((ra_ & 7) << 4)));\
        const int rb_ = wn * 64 + f_ * 16 + (lane & 15);                    \
        b_[f_] = *(const h8*)((Bbuf) + rb_ * 128 + (kb_ ^ ((rb_ & 7) << 4)));\
      }                                                                     \
      _Pragma("unroll")                                                     \
      for (int fm_ = 0; fm_ < 4; ++fm_)                                     \
        _Pragma("unroll")                                                   \
        for (int fn_ = 0; fn_ < 4; ++fn_)                                   \
          acc[fm_][fn_] = MFMA16(a_[fm_], b_[fn_], acc[fm_][fn_]);          \
    }                                                                       \
  } while (0)

  unsigned char* A0 = ldsA[0];  unsigned char* A1 = ldsA[1];
  unsigned char* B0 = ldsB[0];  unsigned char* B1 = ldsB[1];

  STAGE(A0, B0, 0);                       // prologue: 8 loads in flight
  #pragma unroll
  for (int kt = 0; kt < 12; kt += 2) {
    STAGE(A1, B1, kt + 1);                             // prefetch odd tile
    asm volatile("s_waitcnt vmcnt(8)" ::: "memory");   // even tile landed
    __builtin_amdgcn_s_barrier();
    asm volatile("" ::: "memory");
    COMPUTE(A0, B0);
    asm volatile("" ::: "memory");
    __builtin_amdgcn_s_barrier();                      // all waves done reading buf0
    if (kt + 2 < 12) {
      STAGE(A0, B0, kt + 2);                           // prefetch next even tile
      asm volatile("s_waitcnt vmcnt(8)" ::: "memory"); // odd tile landed
    } else {
      asm volatile("s_waitcnt vmcnt(0)" ::: "memory");
    }
    __builtin_amdgcn_s_barrier();
    asm volatile("" ::: "memory");
    COMPUTE(A1, B1);
    asm volatile("" ::: "memory");
    __builtin_amdgcn_s_barrier();                      // all waves done reading buf1
  }
#undef STAGE
#undef COMPUTE

  // epilogue: bias + RoPE (wave spans exactly one head: 64 cols) + f16 store
  const int colb = n0 + wn * 64;
  const int sel = (colb >= 1536) ? 2 : (colb >= 768) ? 1 : 0;
  const float* bias = (sel == 0) ? bqp : (sel == 1) ? bkp : bvp;
  const int hcol = colb % 768;
  float bia[4];
  #pragma unroll
  for (int f = 0; f < 4; ++f) bia[f] = bias[hcol + f * 16 + (lane & 15)];

  #pragma unroll
  for (int fm = 0; fm < 4; ++fm) {
    #pragma unroll
    for (int reg = 0; reg < 4; ++reg) {
      const long m = m0 + wm * 64 + fm * 16 + ((lane >> 4) << 2) + reg;
      const int s = (int)(m % (long)S);
      const int pos = (s < 64) ? s : ((s - 64) & 127);
      unsigned short* orow = QKV + m * N3 + colb;
      if (sel < 2) {  // Q or K: rotate (d, d+32) pairs = (fn, fn+2) same lane
        #pragma unroll
        for (int f = 0; f < 2; ++f) {
          const int d1 = f * 16 + (lane & 15);
          const float c  = rope[(pos * 32 + d1) * 2];
          const float sn = rope[(pos * 32 + d1) * 2 + 1];
          const float x1 = acc[fm][f][reg]     + bia[f];
          const float x2 = acc[fm][f + 2][reg] + bia[f + 2];
          orow[f * 16 + (lane & 15)]       = f2h(x1 * c - x2 * sn);
          orow[(f + 2) * 16 + (lane & 15)] = f2h(x2 * c + x1 * sn);
        }
      } else {        // V: bias only
        #pragma unroll
        for (int f = 0; f < 4; ++f)
          orow[f * 16 + (lane & 15)] = f2h(acc[fm][f][reg] + bia[f]);
      }
    }
  }
}

// ================= attention (one block per (b, window, head)) =================
// 3-phase: [K->LDS once via global_load_lds, V->regs] | [QK^T from LDS] |
// [V^T ds_write overlaps softmax] | [PV]. K and V^T overlay the same 16 KB.
template <int T>
__global__ __launch_bounds__(256) void attn_kernel(
    const unsigned short* __restrict__ QKV, float* __restrict__ out)
{
  constexpr int NF  = T / 16;   // col fragments of scores
  constexpr int NKS = T / 32;   // k-steps of PV
  // phase 1: K [T rows][128 B] row-swizzled ; phase 2: V^T [64 d][256 B]
  __shared__ __align__(16) unsigned char sKV[16384];
  __shared__ __align__(16) unsigned char sP[4][8192];  // per-wave P [32][128] f16, swizzled

  const int tid = threadIdx.x, lane = tid & 63, w = tid >> 6;
  int bid = blockIdx.x;
  const int h = bid % NH; bid /= NH;
  long row0;
  if (T == 64) row0 = (long)bid * S;
  else { const int ww = bid % 64; const int b = bid / 64; row0 = (long)b * S + 64 + (long)ww * 128; }
  const unsigned short* Qb = QKV + row0 * N3 + h * HD;
  const unsigned short* Kb = Qb + H;
  const unsigned short* Vb = Qb + 2 * H;

  // ---- phase A: K -> LDS (linear dest, inverse-swizzled global src); V -> regs ----
  {
    const char* Kc = (const char*)Kb;
    #pragma unroll
    for (int i = 0; i < T / 32; ++i) {
      const int o = i * 4096 + tid * 16;        // linear dest byte
      const int row = o >> 7, cb = o & 127;
      const int csrc = cb ^ ((row & 7) << 4);
      GLL16(Kc + (long)row * (N3 * 2) + csrc, sKV + o);
    }
  }
  us8 va0, va1, vc0, vc1;
  const bool vload = (2 * lane + 1 < T);
  if (vload) {                                  // T14: issue early, write late
    const unsigned short* v0 = Vb + (long)(2 * lane) * N3 + w * 16;
    const unsigned short* v1 = v0 + N3;
    va0 = *(const us8*)(v0);  va1 = *(const us8*)(v0 + 8);
    vc0 = *(const us8*)(v1);  vc1 = *(const us8*)(v1 + 8);
  }
  __syncthreads();                              // K resident (full waitcnt drain)

  const bool active = (w * 32 < T);
  f4 acc[2][NF];
  if (active) {
    // Q fragments straight from global (A-layout: m=lane&15, k=(lane>>4)*8)
    h8 aq[2][2];
    #pragma unroll
    for (int fm = 0; fm < 2; ++fm)
      #pragma unroll
      for (int ks = 0; ks < 2; ++ks) {
        const long r = w * 32 + fm * 16 + (lane & 15);
        aq[fm][ks] = *(const h8*)(Qb + r * N3 + ks * 32 + ((lane >> 4) << 3));
      }
    #pragma unroll
    for (int i = 0; i < 2; ++i)
      #pragma unroll
      for (int f = 0; f < NF; ++f) acc[i][f] = f4z();

    // ---- S = Q K^T, K B-frags from LDS (shared across all waves) ----
    const int kb0 = (lane >> 4) << 4;
    #pragma unroll
    for (int f = 0; f < NF; ++f) {
      const int rk = f * 16 + (lane & 15);
      const int base = rk * 128, sw = (rk & 7) << 4;
      h8 b0 = *(const h8*)(sKV + base + (kb0 ^ sw));
      h8 b1 = *(const h8*)(sKV + base + ((64 + kb0) ^ sw));
      acc[0][f] = MFMA16(aq[0][0], b0, acc[0][f]);
      acc[0][f] = MFMA16(aq[0][1], b1, acc[0][f]);
      acc[1][f] = MFMA16(aq[1][0], b0, acc[1][f]);
      acc[1][f] = MFMA16(aq[1][1], b1, acc[1][f]);
    }
  }
  __syncthreads();                              // all waves done reading K

  // ---- phase B: V^T overlay write (conflict-free b32) + softmax -> sP ----
  if (vload) {
    #pragma unroll
    for (int i = 0; i < 8; ++i) {
      const int d = w * 16 + i, d2 = d + 8;
      *(unsigned*)(sKV + d  * 256 + ((4 * lane) ^ ((d  & 15) << 4))) = (unsigned)va0[i] | ((unsigned)vc0[i] << 16);
      *(unsigned*)(sKV + d2 * 256 + ((4 * lane) ^ ((d2 & 15) << 4))) = (unsigned)va1[i] | ((unsigned)vc1[i] << 16);
    }
  }
  if (active) {
    unsigned char* Pw = sP[w];
    #pragma unroll
    for (int fm = 0; fm < 2; ++fm) {
      #pragma unroll
      for (int reg = 0; reg < 4; ++reg) {
        float mx = -3.0e38f;
        #pragma unroll
        for (int f = 0; f < NF; ++f) mx = fmaxf(mx, acc[fm][f][reg]);
        mx = fmaxf(mx, __shfl_xor(mx, 1));
        mx = fmaxf(mx, __shfl_xor(mx, 2));
        mx = fmaxf(mx, __shfl_xor(mx, 4));
        mx = fmaxf(mx, __shfl_xor(mx, 8));
        float pv[NF], sum = 0.f;
        #pragma unroll
        for (int f = 0; f < NF; ++f) {
          const float p = __expf((acc[fm][f][reg] - mx) * 0.125f);  // /sqrt(64) folded in
          pv[f] = p; sum += p;
        }
        sum += __shfl_xor(sum, 1);
        sum += __shfl_xor(sum, 2);
        sum += __shfl_xor(sum, 4);
        sum += __shfl_xor(sum, 8);
        const float inv = 1.0f / sum;
        const int rloc = fm * 16 + ((lane >> 4) << 2) + reg;
        const int swz = (rloc & 7) << 4;
        #pragma unroll
        for (int f = 0; f < NF; ++f) {
          const int cb = (f * 16 + (lane & 15)) * 2;
          *(unsigned short*)(Pw + rloc * 256 + (cb ^ swz)) = f2h(pv[f] * inv);
        }
      }
    }
  }
  __syncthreads();                              // V^T ready

  if (active) {
    unsigned char* Pw = sP[w];
    // ---- ctx = P V ----
    f4 acc2[2][4];
    #pragma unroll
    for (int i = 0; i < 2; ++i)
      #pragma unroll
      for (int j = 0; j < 4; ++j) acc2[i][j] = f4z();

    #pragma unroll
    for (int ks = 0; ks < NKS; ++ks) {
      h8 pa[2], vb[4];
      const int kb = ks * 64 + ((lane >> 4) << 4);
      #pragma unroll
      for (int fm = 0; fm < 2; ++fm) {
        const int rp = fm * 16 + (lane & 15);
        pa[fm] = *(const h8*)(Pw + rp * 256 + (kb ^ ((rp & 7) << 4)));
      }
      #pragma unroll
      for (int df = 0; df < 4; ++df) {
        const int d = df * 16 + (lane & 15);
        vb[df] = *(const h8*)(sKV + d * 256 + (kb ^ ((d & 15) << 4)));
      }
      #pragma unroll
      for (int fm = 0; fm < 2; ++fm)
        #pragma unroll
        for (int df = 0; df < 4; ++df)
          acc2[fm][df] = MFMA16(pa[fm], vb[df], acc2[fm][df]);
    }

    // ---- write ctx fp32 to [B][S][H] ----
    float* ob = out + (row0 + w * 32) * H + h * HD;
    #pragma unroll
    for (int fm = 0; fm < 2; ++fm)
      #pragma unroll
      for (int df = 0; df < 4; ++df)
        #pragma unroll
        for (int reg = 0; reg < 4; ++reg) {
          const long r = fm * 16 + ((lane >> 4) << 2) + reg;
          const int c = df * 16 + (lane & 15);
          ob[r * H + c] = acc2[fm][df][reg];
        }
  }
}

// ================= launcher =================
extern "C" void kernel_launch(void* const* d_in, const int* in_sizes, int n_in,
                              void* d_out, int out_size, void* d_ws, size_t ws_size,
                              hipStream_t stream) {
  const float* X  = (const float*)d_in[0];
  // d_in[1] = attention_mask (unused by the reference math)
  const float* Wq = (const float*)d_in[2];
  const float* bq = (const float*)d_in[3];
  const float* Wk = (const float*)d_in[4];
  const float* bk = (const float*)d_in[5];
  const float* Wv = (const float*)d_in[6];
  const float* bv = (const float*)d_in[7];
  float* out = (float*)d_out;

  if ((long)ws_size < WS_NEEDED) return;  // clean fail if scratch too small

  char* ws = (char*)d_ws;
  unsigned short* Xb   = (unsigned short*)(ws + XB_OFF);
  unsigned short* Wcat = (unsigned short*)(ws + W_OFF);
  float*          rope = (float*)(ws + ROPE_OFF);
  unsigned short* QKV  = (unsigned short*)(ws + QKV_OFF);

  prep_kernel<<<13264, 256, 0, stream>>>(X, Wq, Wk, Wv, Xb, Wcat, rope);
  qkv_gemm<<<NWG_GEMM, 256, 0, stream>>>(Xb, Wcat, bq, bk, bv, rope, QKV);
  attn_kernel<64><<<B * NH, 256, 0, stream>>>(QKV, out);
  attn_kernel<128><<<B * 64 * NH, 256, 0, stream>>>(QKV, out);
}